// Round 6
// baseline (42.974 us; speedup 1.0000x reference)
//
#include <hip/hip_runtime.h>

#define HOP   256
#define WINL  1024
#define PADL  384
#define NFR   4096
#define EXLEN (NFR * HOP)   // 1048576
#define OUTLEN EXLEN
#define TWOPI_OVER_WIN 0.006135923151542565f  // 2*pi/1024

#define SEGLEN 64     // own samples per segment
#define NSEG   16     // segments per frame
#define WARM   256    // warm-up; worst-case pole radius <=~0.97 -> 0.97^256*|y| ~ 8e-3
#define RND    32     // samples per unrolled round

#define Y_OFF  ((size_t)WINL * NFR)   // float offset of y region in ws (xT first)

// ---------------- pass 0: xT[t][f] = ex[f*HOP + t - PADL] (0 outside) ----------------
// LDS-tiled 64x64 transpose; both global sides coalesced; pad 65 kills bank conflicts.
__global__ __launch_bounds__(256) void transpose_ex(const float* __restrict__ ex,
                                                    float* __restrict__ xT) {
    __shared__ float lds[64 * 65];
    const int bt = blockIdx.x & 15;       // t-tile (16)
    const int bf = blockIdx.x >> 4;       // f-tile (64)
    const int T = bt * 64, F = bf * 64;
    const int tid = threadIdx.x;
#pragma unroll
    for (int q = 0; q < 4; ++q) {
        const int flat = q * 1024 + tid * 4;   // [0,4096)
        const int fl = flat >> 6;              // frame-local 0..63
        const int dt = flat & 63;              // 4-aligned
        const int g = (F + fl) * HOP + T - PADL + dt;  // 4-aligned; OOB all-or-nothing
        float4 v = make_float4(0.f, 0.f, 0.f, 0.f);
        if ((unsigned)g < (unsigned)EXLEN)
            v = *reinterpret_cast<const float4*>(ex + g);
        lds[(dt + 0) * 65 + fl] = v.x;
        lds[(dt + 1) * 65 + fl] = v.y;
        lds[(dt + 2) * 65 + fl] = v.z;
        lds[(dt + 3) * 65 + fl] = v.w;
    }
    __syncthreads();
#pragma unroll
    for (int q = 0; q < 4; ++q) {
        const int idx4 = q * 256 + tid;        // [0,1024) = 64 dt x 16 fq
        const int dt = idx4 >> 4;
        const int fq = idx4 & 15;
        float4 v;
        v.x = lds[dt * 65 + fq * 4 + 0];
        v.y = lds[dt * 65 + fq * 4 + 1];
        v.z = lds[dt * 65 + fq * 4 + 2];
        v.w = lds[dt * 65 + fq * 4 + 3];
        *reinterpret_cast<float4*>(xT + (size_t)(T + dt) * NFR + F + fq * 4) = v;
    }
}

// ---------------- filter: reads lane-coalesced xT columns ----------------
// One thread = one (frame, segment). y_t = gain*x_t - sum_{d=1..25} a_d y_{t-d};
// taps d=2..25 in 3 independent chains, d=1 last (cross-sample path = 1 FMA).
__global__ __launch_bounds__(64, 1) void lpc_seg_xt(const float* __restrict__ xT,
                                                    const float* __restrict__ lpc,
                                                    float* __restrict__ y) {
    const int bx = blockIdx.x;
    const int fg = bx >> 4;          // frame group (64 frames)
    const int k  = bx & 15;          // segment index
    const int f  = fg * 64 + threadIdx.x;

    const float* lp = lpc + f * 26;
    const float gain = lp[0];
    float a[26];
#pragma unroll
    for (int i = 1; i <= 25; ++i) a[i] = lp[i];

    const int own = k * SEGLEN;
    int tstart = own - WARM; if (tstart < 0) tstart = 0;
    const int nrounds = (own + SEGLEN - tstart) >> 5;   // 2..10, always even
    const float* __restrict__ xcol = xT + f;            // column f; sample t at xcol[t*NFR]

    float yP[RND], yC[RND];
#pragma unroll
    for (int i = 0; i < RND; ++i) { yP[i] = 0.0f; yC[i] = 0.0f; }

    float xA[RND], xB[RND];
    {
        const float* p = xcol + (size_t)tstart * NFR;
#pragma unroll
        for (int i = 0; i < RND; ++i) xA[i] = p[(size_t)i * NFR];
    }

    auto ROUND = [&](float (&XC)[RND], float (&XN)[RND],
                     float (&Yp)[RND], float (&Yc)[RND], int t0) {
        if (t0 + 2 * RND <= WINL) {            // wave-uniform; skip only final OOB prefetch
            const float* p = xcol + (size_t)(t0 + RND) * NFR;
#pragma unroll
            for (int i = 0; i < RND; ++i) XN[i] = p[(size_t)i * NFR];
        }
#pragma unroll
        for (int i = 0; i < RND; ++i) {
            float p0 = gain * XC[i], p1 = 0.0f, p2 = 0.0f;
#pragma unroll
            for (int d = 2; d <= 9; ++d) {
                const int j = i - d;
                p0 = fmaf(-a[d], (j >= 0) ? Yc[j] : Yp[RND + j], p0);
            }
#pragma unroll
            for (int d = 10; d <= 17; ++d) {
                const int j = i - d;
                p1 = fmaf(-a[d], (j >= 0) ? Yc[j] : Yp[RND + j], p1);
            }
#pragma unroll
            for (int d = 18; d <= 25; ++d) {
                const int j = i - d;
                p2 = fmaf(-a[d], (j >= 0) ? Yc[j] : Yp[RND + j], p2);
            }
            const float ym1 = (i >= 1) ? Yc[i - 1] : Yp[RND - 1];
            Yc[i] = fmaf(-a[1], ym1, p0 + (p1 + p2));
        }
        if (t0 >= own) {   // uniform per wave
            float4* dst = reinterpret_cast<float4*>(y + (size_t)f * WINL + t0);
#pragma unroll
            for (int q = 0; q < RND / 4; ++q)
                dst[q] = make_float4(Yc[4 * q], Yc[4 * q + 1], Yc[4 * q + 2], Yc[4 * q + 3]);
        }
    };

    int t0 = tstart;
    const int half = nrounds >> 1;
    for (int h = 0; h < half; ++h) {
        ROUND(xA, xB, yP, yC, t0); t0 += RND;
        ROUND(xB, xA, yC, yP, t0); t0 += RND;
    }
}

// ---------------- round-5 proven fallback filter (direct ex) ----------------
__device__ __forceinline__ float4 gld4(const float* __restrict__ ex, int idx) {
    if ((unsigned)idx < (unsigned)EXLEN)
        return *reinterpret_cast<const float4*>(ex + idx);
    return make_float4(0.0f, 0.0f, 0.0f, 0.0f);
}

__global__ __launch_bounds__(64, 1) void lpc_seg(const float* __restrict__ ex,
                                                 const float* __restrict__ lpc,
                                                 float* __restrict__ y) {
    const int bx = blockIdx.x;
    const int fg = bx >> 4;
    const int k  = bx & 15;
    const int f  = fg * 64 + threadIdx.x;

    const float* lp = lpc + f * 26;
    const float gain = lp[0];
    float a[26];
#pragma unroll
    for (int i = 1; i <= 25; ++i) a[i] = lp[i];

    const int own = k * SEGLEN;
    int tstart = own - WARM; if (tstart < 0) tstart = 0;
    const int nrounds = (own + SEGLEN - tstart) >> 5;
    const int xbase = f * HOP - PADL;

    float yP[RND], yC[RND];
#pragma unroll
    for (int i = 0; i < RND; ++i) { yP[i] = 0.0f; yC[i] = 0.0f; }

    float xA[RND], xB[RND];
    {
        const int nb0 = xbase + tstart;
#pragma unroll
        for (int q = 0; q < RND / 4; ++q) {
            const float4 v = gld4(ex, nb0 + 4 * q);
            xA[4 * q + 0] = v.x; xA[4 * q + 1] = v.y;
            xA[4 * q + 2] = v.z; xA[4 * q + 3] = v.w;
        }
    }

    auto ROUND = [&](float (&XC)[RND], float (&XN)[RND],
                     float (&Yp)[RND], float (&Yc)[RND], int t0) {
        const int nb = xbase + t0 + RND;
#pragma unroll
        for (int q = 0; q < RND / 4; ++q) {
            const float4 v = gld4(ex, nb + 4 * q);
            XN[4 * q + 0] = v.x; XN[4 * q + 1] = v.y;
            XN[4 * q + 2] = v.z; XN[4 * q + 3] = v.w;
        }
#pragma unroll
        for (int i = 0; i < RND; ++i) {
            float p0 = gain * XC[i], p1 = 0.0f, p2 = 0.0f;
#pragma unroll
            for (int d = 2; d <= 9; ++d) {
                const int j = i - d;
                p0 = fmaf(-a[d], (j >= 0) ? Yc[j] : Yp[RND + j], p0);
            }
#pragma unroll
            for (int d = 10; d <= 17; ++d) {
                const int j = i - d;
                p1 = fmaf(-a[d], (j >= 0) ? Yc[j] : Yp[RND + j], p1);
            }
#pragma unroll
            for (int d = 18; d <= 25; ++d) {
                const int j = i - d;
                p2 = fmaf(-a[d], (j >= 0) ? Yc[j] : Yp[RND + j], p2);
            }
            const float ym1 = (i >= 1) ? Yc[i - 1] : Yp[RND - 1];
            Yc[i] = fmaf(-a[1], ym1, p0 + (p1 + p2));
        }
        if (t0 >= own) {
            float4* dst = reinterpret_cast<float4*>(y + (size_t)f * WINL + t0);
#pragma unroll
            for (int q = 0; q < RND / 4; ++q)
                dst[q] = make_float4(Yc[4 * q], Yc[4 * q + 1], Yc[4 * q + 2], Yc[4 * q + 3]);
        }
    };

    int t0 = tstart;
    const int half = nrounds >> 1;
    for (int h = 0; h < half; ++h) {
        ROUND(xA, xB, yP, yC, t0); t0 += RND;
        ROUND(xB, xA, yC, yP, t0); t0 += RND;
    }
}

// ---------------- gather: <=4 windowed contributions; analytic Hann + norm ----------------
__global__ __launch_bounds__(256) void ola_gather(const float* __restrict__ ws,
                                                  float* __restrict__ out) {
    int tid = blockIdx.x * 256 + threadIdx.x;
    int i4 = tid * 4;
    if (i4 >= OUTLEN) return;
    int p  = i4 + PADL;
    int fp = p >> 8;
    int r  = p & 255;       // 4-aligned; r..r+3 never crosses a 256 boundary
    float cth[4], sth[4];
#pragma unroll
    for (int e = 0; e < 4; ++e)
        __sincosf(TWOPI_OVER_WIN * (float)(r + e), &sth[e], &cth[e]);
    float num[4] = {0.f, 0.f, 0.f, 0.f};
    float den[4] = {0.f, 0.f, 0.f, 0.f};
#pragma unroll
    for (int j = 0; j < 4; ++j) {
        int f = fp - j;
        if (f >= 0 && f < NFR) {
            const float4 yv = *reinterpret_cast<const float4*>(
                ws + (size_t)f * WINL + (r + 256 * j));
            float yy[4] = {yv.x, yv.y, yv.z, yv.w};
#pragma unroll
            for (int e = 0; e < 4; ++e) {
                float w;
                if      (j == 0) w = 0.5f - 0.5f * cth[e];
                else if (j == 1) w = 0.5f + 0.5f * sth[e];
                else if (j == 2) w = 0.5f + 0.5f * cth[e];
                else             w = 0.5f - 0.5f * sth[e];
                num[e] = fmaf(yy[e], w, num[e]);
                den[e] += w;
            }
        }
    }
    float4 o;
    o.x = num[0] / den[0];
    o.y = num[1] / den[1];
    o.z = num[2] / den[2];
    o.w = num[3] / den[3];
    *reinterpret_cast<float4*>(out + i4) = o;
}

extern "C" void kernel_launch(void* const* d_in, const int* in_sizes, int n_in,
                              void* d_out, int out_size, void* d_ws, size_t ws_size,
                              hipStream_t stream) {
    const float* ex  = (const float*)d_in[0];
    const float* lpc = (const float*)d_in[1];
    float* out = (float*)d_out;
    const size_t need = 2 * Y_OFF * sizeof(float);   // xT (16 MiB) + y (16 MiB)
    if (ws_size >= need) {
        float* xT = (float*)d_ws;
        float* yb = (float*)d_ws + Y_OFF;
        transpose_ex<<<1024, 256, 0, stream>>>(ex, xT);
        lpc_seg_xt<<<(NFR / 64) * NSEG, 64, 0, stream>>>(xT, lpc, yb);
        ola_gather<<<(OUTLEN / 4) / 256, 256, 0, stream>>>(yb, out);
    } else {
        float* yb = (float*)d_ws;                    // round-5 proven path
        lpc_seg<<<(NFR / 64) * NSEG, 64, 0, stream>>>(ex, lpc, yb);
        ola_gather<<<(OUTLEN / 4) / 256, 256, 0, stream>>>(yb, out);
    }
}

// Round 7
// 34.409 us; speedup vs baseline: 1.2489x; 1.2489x over previous
//
#include <hip/hip_runtime.h>

#define HOP   256
#define WINL  1024
#define PADL  384
#define NFR   4096
#define EXLEN (NFR * HOP)   // 1048576
#define OUTLEN EXLEN
#define TWOPI_OVER_WIN 0.006135923151542565f  // 2*pi/1024

#define SEGLEN 64     // own samples per segment
#define NSEG   16     // segments per frame
#define WARM   192    // warm-up; bound rho^192*A <= 0.034 given absmax floor at WARM=256
#define RND    32     // samples per unrolled round

__device__ __forceinline__ float4 gld4(const float* __restrict__ ex, int idx) {
    // idx is always 4-aligned; OOB regions are 4-aligned => all-or-nothing.
    if ((unsigned)idx < (unsigned)EXLEN)
        return *reinterpret_cast<const float4*>(ex + idx);
    return make_float4(0.0f, 0.0f, 0.0f, 0.0f);
}

// One thread = one (frame, segment). Plain reference recurrence:
//   y_t = gain*x_t - sum_{d=1..25} a_d y_{t-d}
// taps d=2..25 in 3 independent partial chains; d=1 applied last so the
// cross-sample critical path is a single FMA.
// amdgpu_waves_per_eu(1,1): we launch exactly 1 wave/SIMD by construction;
// let regalloc use the full VGPR file so the x-prefetch stays in registers.
__global__ __attribute__((amdgpu_waves_per_eu(1, 1))) __launch_bounds__(64)
void lpc_seg(const float* __restrict__ ex,
             const float* __restrict__ lpc,
             float* __restrict__ y) {
    const int bx = blockIdx.x;
    const int fg = bx >> 4;          // frame group (64 frames)
    const int k  = bx & 15;          // segment index
    const int l  = threadIdx.x;
    const int f  = fg * 64 + l;

    // ---- stage this block's 64 lpc rows through LDS (coalesced global reads;
    //      row pad 26->27 makes per-lane ds_reads conflict-free; single wave,
    //      so no barrier needed) ----
    __shared__ float lcoef[64 * 27];
    {
        const float* __restrict__ src = lpc + (size_t)fg * 64 * 26;
#pragma unroll
        for (int i = l; i < 64 * 26; i += 64)
            lcoef[(i / 26) * 27 + (i % 26)] = src[i];
    }
    const float* __restrict__ myc = lcoef + l * 27;
    const float gain = myc[0];
    float a[26];
#pragma unroll
    for (int i = 1; i <= 25; ++i) a[i] = myc[i];

    const int own = k * SEGLEN;
    int tstart = own - WARM; if (tstart < 0) tstart = 0;
    const int nrounds = (own + SEGLEN - tstart) >> 5;   // 2..8, always even
    const int xbase = f * HOP - PADL;                   // ex index of frame-sample 0

    float yP[RND], yC[RND];
#pragma unroll
    for (int i = 0; i < RND; ++i) { yP[i] = 0.0f; yC[i] = 0.0f; }

    float xA[RND], xB[RND];
    {
        const int nb0 = xbase + tstart;
#pragma unroll
        for (int q = 0; q < RND / 4; ++q) {
            const float4 v = gld4(ex, nb0 + 4 * q);
            xA[4 * q + 0] = v.x; xA[4 * q + 1] = v.y;
            xA[4 * q + 2] = v.z; xA[4 * q + 3] = v.w;
        }
    }

    auto ROUND = [&](float (&XC)[RND], float (&XN)[RND],
                     float (&Yp)[RND], float (&Yc)[RND], int t0) {
        const int nb = xbase + t0 + RND;   // prefetch next round's x
#pragma unroll
        for (int q = 0; q < RND / 4; ++q) {
            const float4 v = gld4(ex, nb + 4 * q);
            XN[4 * q + 0] = v.x; XN[4 * q + 1] = v.y;
            XN[4 * q + 2] = v.z; XN[4 * q + 3] = v.w;
        }
#pragma unroll
        for (int i = 0; i < RND; ++i) {
            float p0 = gain * XC[i], p1 = 0.0f, p2 = 0.0f;
#pragma unroll
            for (int d = 2; d <= 9; ++d) {
                const int j = i - d;                     // static after unroll
                p0 = fmaf(-a[d], (j >= 0) ? Yc[j] : Yp[RND + j], p0);
            }
#pragma unroll
            for (int d = 10; d <= 17; ++d) {
                const int j = i - d;
                p1 = fmaf(-a[d], (j >= 0) ? Yc[j] : Yp[RND + j], p1);
            }
#pragma unroll
            for (int d = 18; d <= 25; ++d) {
                const int j = i - d;
                p2 = fmaf(-a[d], (j >= 0) ? Yc[j] : Yp[RND + j], p2);
            }
            const float ym1 = (i >= 1) ? Yc[i - 1] : Yp[RND - 1];
            Yc[i] = fmaf(-a[1], ym1, p0 + (p1 + p2));
        }
        if (t0 >= own) {   // uniform per wave
            float4* dst = reinterpret_cast<float4*>(y + (size_t)f * WINL + t0);
#pragma unroll
            for (int q = 0; q < RND / 4; ++q)
                dst[q] = make_float4(Yc[4 * q], Yc[4 * q + 1], Yc[4 * q + 2], Yc[4 * q + 3]);
        }
    };

    int t0 = tstart;
    const int half = nrounds >> 1;
    for (int h = 0; h < half; ++h) {
        ROUND(xA, xB, yP, yC, t0); t0 += RND;
        ROUND(xB, xA, yC, yP, t0); t0 += RND;
    }
}

// ---------------- gather: <=4 windowed contributions; analytic Hann + norm ----------------
__global__ __launch_bounds__(256) void ola_gather(const float* __restrict__ ws,
                                                  float* __restrict__ out) {
    int tid = blockIdx.x * 256 + threadIdx.x;
    int i4 = tid * 4;
    if (i4 >= OUTLEN) return;
    int p  = i4 + PADL;
    int fp = p >> 8;
    int r  = p & 255;       // 4-aligned; r..r+3 never crosses a 256 boundary
    float cth[4], sth[4];
#pragma unroll
    for (int e = 0; e < 4; ++e)
        __sincosf(TWOPI_OVER_WIN * (float)(r + e), &sth[e], &cth[e]);
    float num[4] = {0.f, 0.f, 0.f, 0.f};
    float den[4] = {0.f, 0.f, 0.f, 0.f};
#pragma unroll
    for (int j = 0; j < 4; ++j) {
        int f = fp - j;
        if (f >= 0 && f < NFR) {
            const float4 yv = *reinterpret_cast<const float4*>(
                ws + (size_t)f * WINL + (r + 256 * j));
            float yy[4] = {yv.x, yv.y, yv.z, yv.w};
#pragma unroll
            for (int e = 0; e < 4; ++e) {
                float w;
                if      (j == 0) w = 0.5f - 0.5f * cth[e];
                else if (j == 1) w = 0.5f + 0.5f * sth[e];
                else if (j == 2) w = 0.5f + 0.5f * cth[e];
                else             w = 0.5f - 0.5f * sth[e];
                num[e] = fmaf(yy[e], w, num[e]);
                den[e] += w;
            }
        }
    }
    float4 o;
    o.x = num[0] / den[0];
    o.y = num[1] / den[1];
    o.z = num[2] / den[2];
    o.w = num[3] / den[3];
    *reinterpret_cast<float4*>(out + i4) = o;
}

extern "C" void kernel_launch(void* const* d_in, const int* in_sizes, int n_in,
                              void* d_out, int out_size, void* d_ws, size_t ws_size,
                              hipStream_t stream) {
    const float* ex  = (const float*)d_in[0];
    const float* lpc = (const float*)d_in[1];
    float* out = (float*)d_out;
    float* yb  = (float*)d_ws;   // 16 MiB: y[f][t], fully overwritten each call
    lpc_seg<<<(NFR / 64) * NSEG, 64, 0, stream>>>(ex, lpc, yb);
    ola_gather<<<(OUTLEN / 4) / 256, 256, 0, stream>>>(yb, out);
}